// Round 3
// baseline (341.547 us; speedup 1.0000x reference)
//
#include <hip/hip_runtime.h>
#include <hip/hip_bf16.h>
#include <stdint.h>

typedef unsigned short u16;
typedef __attribute__((ext_vector_type(8))) short bf16x8;
typedef __attribute__((ext_vector_type(4))) float f32x4;

#define NN 8192
#define HH 256
#define KK 100
#define BB 32
#define LL 128
#define NPAD 1024
#define SPLITK 8
#define KCH (NN / SPLITK)   // 1024
#define STEPS1 (KCH / 128)  // 8
#define STEPS2 (512 / 128)  // 4

// raw barrier: waits LDS ops only; leaves global prefetch loads in flight (no vmcnt drain)
#define BARRIER() asm volatile("s_waitcnt lgkmcnt(0)\ns_barrier" ::: "memory")

__device__ __forceinline__ u16 f2bf_rne(float x) {
  union { __hip_bfloat16 h; u16 u; } v;
  v.h = __float2bfloat16(x);
  return v.u;
}

__device__ __forceinline__ bf16x8 pack8(float4 a, float4 b) {
  bf16x8 r;
  r[0] = (short)f2bf_rne(a.x); r[1] = (short)f2bf_rne(a.y);
  r[2] = (short)f2bf_rne(a.z); r[3] = (short)f2bf_rne(a.w);
  r[4] = (short)f2bf_rne(b.x); r[5] = (short)f2bf_rne(b.y);
  r[6] = (short)f2bf_rne(b.z); r[7] = (short)f2bf_rne(b.w);
  return r;
}

// ---------------------------------------------------------------- embT: [256][8192] bf16 = emb^T
__global__ __launch_bounds__(256) void convert_embT(const float* __restrict__ emb,
                                                    u16* __restrict__ embT) {
  __shared__ float t[64][65];
  const int tid = threadIdx.x;
  const int k0 = blockIdx.x * 64, n0 = blockIdx.y * 64;
#pragma unroll
  for (int i = 0; i < 16; ++i) {
    int idx = i * 256 + tid;
    int r = idx >> 6, c = idx & 63;
    t[r][c] = emb[(size_t)(k0 + r) * HH + n0 + c];
  }
  __syncthreads();
#pragma unroll
  for (int i = 0; i < 16; ++i) {
    int idx = i * 256 + tid;
    int r = idx >> 6, c = idx & 63;
    embT[(size_t)(n0 + r) * NN + k0 + c] = f2bf_rne(t[c][r]);
  }
}

// ---------------------------------------------------------------- layer1 = adj @ emb (bf16 MFMA)
// BM=128, BN=256(all H), BK=128, 1024 thr (16 waves 4Mx4N), split-K=8, grid (64,8).
// A: fp32->reg 2-deep prefetch -> convert -> dbuf LDS. B: direct from L2 (embT).
__global__ __launch_bounds__(1024, 4) void gemm_layer1(const float* __restrict__ adj,
                                                       const u16* __restrict__ embT,
                                                       float* __restrict__ parts) {
  __shared__ __align__(16) u16 As0[128 * 128];
  __shared__ __align__(16) u16 As1[128 * 128];
  const int tid = threadIdx.x;
  const int lane = tid & 63, wid = tid >> 6;
  const int wm = wid >> 2, wn = wid & 3;
  const int m0 = blockIdx.x * 128;
  const int kbeg = blockIdx.y * KCH;

  // A staging map: thread -> (row ra, 16 consecutive k at kc)
  const int ra = tid >> 3;
  const int kc = (tid & 7) << 4;
  const int swa = (ra & 7) << 3;
  const float4* ap = reinterpret_cast<const float4*>(adj + (size_t)(m0 + ra) * NN + kbeg + kc);

  // B direct pointers (one per ni)
  const int bk8 = (lane >> 4) << 3;
  const u16* bp0 = embT + (size_t)(wn * 64 + (lane & 15)) * NN + kbeg + bk8;
  const u16* bp1 = bp0 + (size_t)16 * NN;
  const u16* bp2 = bp1 + (size_t)16 * NN;
  const u16* bp3 = bp2 + (size_t)16 * NN;

  // A fragment read map
  const int arow0 = wm * 32 + (lane & 15);
  const int asw = (arow0 & 7) << 3;
  const int abase0 = arow0 * 128;
  const int abase1 = abase0 + 16 * 128;

  f32x4 acc[2][4];
  const f32x4 zf = {0.f, 0.f, 0.f, 0.f};
#pragma unroll
  for (int i = 0; i < 2; ++i)
#pragma unroll
    for (int j = 0; j < 4; ++j) acc[i][j] = zf;

  float4 pA0, pA1, pA2, pA3, pB0, pB1, pB2, pB3;

  auto LOADA = [&](float4& x0, float4& x1, float4& x2, float4& x3, int s) {
    const float4* p = ap + s * 32;
    x0 = p[0]; x1 = p[1]; x2 = p[2]; x3 = p[3];
  };
  auto STOREA = [&](u16* buf, float4 x0, float4 x1, float4 x2, float4 x3) {
    *reinterpret_cast<bf16x8*>(&buf[ra * 128 + (kc ^ swa)]) = pack8(x0, x1);
    *reinterpret_cast<bf16x8*>(&buf[ra * 128 + ((kc + 8) ^ swa)]) = pack8(x2, x3);
  };
  auto COMPUTE = [&](const u16* buf, int s) {
#pragma unroll
    for (int kk = 0; kk < 128; kk += 32) {
      bf16x8 b0 = *reinterpret_cast<const bf16x8*>(bp0 + s * 128 + kk);
      bf16x8 b1 = *reinterpret_cast<const bf16x8*>(bp1 + s * 128 + kk);
      bf16x8 b2 = *reinterpret_cast<const bf16x8*>(bp2 + s * 128 + kk);
      bf16x8 b3 = *reinterpret_cast<const bf16x8*>(bp3 + s * 128 + kk);
      const int ke = (kk + bk8) ^ asw;
      bf16x8 a0 = *reinterpret_cast<const bf16x8*>(&buf[abase0 + ke]);
      bf16x8 a1 = *reinterpret_cast<const bf16x8*>(&buf[abase1 + ke]);
      acc[0][0] = __builtin_amdgcn_mfma_f32_16x16x32_bf16(a0, b0, acc[0][0], 0, 0, 0);
      acc[0][1] = __builtin_amdgcn_mfma_f32_16x16x32_bf16(a0, b1, acc[0][1], 0, 0, 0);
      acc[0][2] = __builtin_amdgcn_mfma_f32_16x16x32_bf16(a0, b2, acc[0][2], 0, 0, 0);
      acc[0][3] = __builtin_amdgcn_mfma_f32_16x16x32_bf16(a0, b3, acc[0][3], 0, 0, 0);
      acc[1][0] = __builtin_amdgcn_mfma_f32_16x16x32_bf16(a1, b0, acc[1][0], 0, 0, 0);
      acc[1][1] = __builtin_amdgcn_mfma_f32_16x16x32_bf16(a1, b1, acc[1][1], 0, 0, 0);
      acc[1][2] = __builtin_amdgcn_mfma_f32_16x16x32_bf16(a1, b2, acc[1][2], 0, 0, 0);
      acc[1][3] = __builtin_amdgcn_mfma_f32_16x16x32_bf16(a1, b3, acc[1][3], 0, 0, 0);
    }
  };

  LOADA(pA0, pA1, pA2, pA3, 0);
  LOADA(pB0, pB1, pB2, pB3, 1);
  STOREA(As0, pA0, pA1, pA2, pA3);
  BARRIER();
#pragma unroll
  for (int s = 0; s < STEPS1; s += 2) {
    if (s + 2 < STEPS1) LOADA(pA0, pA1, pA2, pA3, s + 2);
    COMPUTE(As0, s);
    if (s + 1 < STEPS1) STOREA(As1, pB0, pB1, pB2, pB3);
    BARRIER();
    if (s + 3 < STEPS1) LOADA(pB0, pB1, pB2, pB3, s + 3);
    if (s + 1 < STEPS1) COMPUTE(As1, s + 1);
    if (s + 2 < STEPS1) STOREA(As0, pA0, pA1, pA2, pA3);
    BARRIER();
  }

  float* out = parts + (size_t)blockIdx.y * ((size_t)NN * HH);
  const int r0 = (lane >> 4) << 2;
  const int colw = wn * 64 + (lane & 15);
#pragma unroll
  for (int mi = 0; mi < 2; ++mi)
#pragma unroll
    for (int ni = 0; ni < 4; ++ni)
#pragma unroll
      for (int r = 0; r < 4; ++r)
        out[(size_t)(m0 + wm * 32 + mi * 16 + r0 + r) * HH + colw + ni * 16] = acc[mi][ni][r];
}

// ---------------------------------------------------------------- gather: Q/A rows = sum of split-K parts
__global__ __launch_bounds__(256) void gather_qa(const float* __restrict__ parts,
                                                 const int* __restrict__ q_idx,
                                                 const int* __restrict__ a_idx,
                                                 float* __restrict__ Q, float* __restrict__ A) {
  const int rb = blockIdx.x;
  const bool isA = rb >= BB * LL;
  const int r = isA ? rb - BB * LL : rb;
  const int idx = (isA ? a_idx : q_idx)[r];
  const int tid = threadIdx.x;
  float s = 0.f;
#pragma unroll
  for (int p = 0; p < SPLITK; ++p)
    s += parts[(size_t)p * ((size_t)NN * HH) + (size_t)idx * HH + tid];
  (isA ? A : Q)[(size_t)r * HH + tid] = s;
}

// ---------------------------------------------------------------- score + row softmax fused
__global__ __launch_bounds__(128) void score_row(const float* __restrict__ Q,
                                                 const float* __restrict__ A,
                                                 float* __restrict__ score,
                                                 float* __restrict__ wq) {
  __shared__ float qs[HH];
  __shared__ float red[4];
  const int bl = blockIdx.x;
  const int b = bl >> 7;
  const int tid = threadIdx.x;
  const int wv = tid >> 6, lane = tid & 63;
  qs[tid] = Q[(size_t)bl * HH + tid];
  qs[tid + 128] = Q[(size_t)bl * HH + tid + 128];
  __syncthreads();
  const float4* a4 = reinterpret_cast<const float4*>(A + ((size_t)b * LL + tid) * HH);
  const float4* q4 = reinterpret_cast<const float4*>(qs);
  float acc = 0.f;
#pragma unroll 8
  for (int h = 0; h < HH / 4; ++h) {
    float4 av = a4[h], qv = q4[h];
    acc += av.x * qv.x + av.y * qv.y + av.z * qv.z + av.w * qv.w;
  }
  float mx = acc;
#pragma unroll
  for (int off = 32; off; off >>= 1) mx = fmaxf(mx, __shfl_xor(mx, off));
  if (lane == 0) red[wv] = mx;
  __syncthreads();
  mx = fmaxf(red[0], red[1]);
  float e = expf(acc - mx);
  float sm = e;
#pragma unroll
  for (int off = 32; off; off >>= 1) sm += __shfl_xor(sm, off);
  if (lane == 0) red[2 + wv] = sm;
  __syncthreads();
  sm = red[2] + red[3];
  score[(size_t)bl * LL + tid] = acc;
  wq[(size_t)bl * LL + tid] = e / sm;
}

// ---------------------------------------------------------------- softmax over l (cols) -> waT[b][m][l]
__global__ __launch_bounds__(64) void softmax_col(const float* __restrict__ score,
                                                  float* __restrict__ waT) {
  const int bm = blockIdx.x;
  const int b = bm >> 7, m = bm & 127;
  const int lane = threadIdx.x;
  const float* s = score + (size_t)b * LL * LL + m;
  float x0 = s[(size_t)lane * LL], x1 = s[(size_t)(lane + 64) * LL];
  float mx = fmaxf(x0, x1);
#pragma unroll
  for (int off = 32; off; off >>= 1) mx = fmaxf(mx, __shfl_xor(mx, off));
  float e0 = expf(x0 - mx), e1 = expf(x1 - mx);
  float sum = e0 + e1;
#pragma unroll
  for (int off = 32; off; off >>= 1) sum += __shfl_xor(sum, off);
  float inv = 1.f / sum;
  waT[(size_t)bm * LL + lane] = e0 * inv;
  waT[(size_t)bm * LL + lane + 64] = e1 * inv;
}

// ---------------------------------------------------------------- align+encode: EQ/EA + match features -> Tbf
// grid 256: side(2) x b(32) x htile(4). 1024 thr = 16 lt x 64 hx. LDS 96 KB.
__global__ __launch_bounds__(1024) void align_encode(const float* __restrict__ wq,
                                                     const float* __restrict__ waT,
                                                     const float* __restrict__ Q,
                                                     const float* __restrict__ A,
                                                     u16* __restrict__ Tbf) {
  __shared__ float wl[128 * 128];   // 64 KB: weights, [out_row][sum_idx]
  __shared__ float sl[128 * 64];    // 32 KB: source tile [sum_idx][h]
  const int bid = blockIdx.x;
  const int side = bid >> 7;          // 0 = EQ (tq), 1 = EA (ta)
  const int b = (bid >> 2) & 31;
  const int h0 = (bid & 3) * 64;
  const int tid = threadIdx.x;
  const int lt = tid >> 6, hx = tid & 63;

  const float* wsrc = (side ? waT : wq) + (size_t)b * (LL * LL);
  const float* ssrc = (side ? Q : A) + (size_t)b * (LL * HH) + h0;
  const float* msrc = (side ? A : Q) + (size_t)b * (LL * HH) + h0;

#pragma unroll
  for (int i = 0; i < 16; ++i) {
    int idx = i * 1024 + tid;
    wl[idx] = wsrc[idx];
  }
#pragma unroll
  for (int i = 0; i < 8; ++i) {
    int idx = i * 1024 + tid;
    int r = idx >> 6, c = idx & 63;
    sl[idx] = ssrc[(size_t)r * HH + c];
  }
  __syncthreads();

  float accv[8];
#pragma unroll
  for (int ii = 0; ii < 8; ++ii) accv[ii] = 0.f;

  for (int j4 = 0; j4 < 128; j4 += 4) {
    float s0 = sl[(j4 + 0) * 64 + hx];
    float s1 = sl[(j4 + 1) * 64 + hx];
    float s2 = sl[(j4 + 2) * 64 + hx];
    float s3 = sl[(j4 + 3) * 64 + hx];
#pragma unroll
    for (int ii = 0; ii < 8; ++ii) {
      float4 wv = *reinterpret_cast<const float4*>(&wl[(lt + 16 * ii) * 128 + j4]);
      accv[ii] += wv.x * s0 + wv.y * s1 + wv.z * s2 + wv.w * s3;
    }
  }

  u16* outp = Tbf + (size_t)(side * 4096 + b * 128) * 512 + h0;
#pragma unroll
  for (int ii = 0; ii < 8; ++ii) {
    int i = lt + 16 * ii;
    float mv = msrc[(size_t)i * HH + hx];
    float e = accv[ii];
    float d = mv - e;
    outp[(size_t)i * 512 + hx] = f2bf_rne(d * d);
    outp[(size_t)i * 512 + 256 + hx] = f2bf_rne(mv * e);
  }
}

// ---------------------------------------------------------------- Wcat bf16 [1024][512]
__global__ __launch_bounds__(256) void prep_wcat(const float* __restrict__ w0,
                                                 const float* __restrict__ w1,
                                                 const float* __restrict__ w2,
                                                 const float* __restrict__ w3,
                                                 u16* __restrict__ Wcat) {
  const int kr = blockIdx.x;
  const int tid = threadIdx.x;
  u16* out = Wcat + (size_t)kr * 512;
  if (kr >= KK * 10) {
    out[tid] = 0;
    out[tid + 256] = 0;
    return;
  }
  const int k = kr / 10, s = kr % 10;
  const float* w;
  int r, fs;
  if (s < 1)      { w = w0; r = s;     fs = 1; }
  else if (s < 3) { w = w1; r = s - 1; fs = 2; }
  else if (s < 6) { w = w2; r = s - 3; fs = 3; }
  else            { w = w3; r = s - 6; fs = 4; }
  const float* src = w + ((size_t)k * fs + r) * 522 + 5;
  out[tid] = f2bf_rne(src[tid]);
  out[tid + 256] = f2bf_rne(src[tid + 256]);
}

// ---------------------------------------------------------------- conv GEMM: D[8192][1024] = Tbf @ Wcat^T
// Same structure as gemm_layer1; A bf16 (no convert), B = Wcat direct from L2. grid (64,4).
__global__ __launch_bounds__(1024, 4) void gemm_conv(const u16* __restrict__ Tbf,
                                                     const u16* __restrict__ Wcat,
                                                     float* __restrict__ D) {
  __shared__ __align__(16) u16 As0[128 * 128];
  __shared__ __align__(16) u16 As1[128 * 128];
  const int tid = threadIdx.x;
  const int lane = tid & 63, wid = tid >> 6;
  const int wm = wid >> 2, wn = wid & 3;
  const int m0 = blockIdx.x * 128;
  const int n0 = blockIdx.y * 256;

  const int ra = tid >> 3;
  const int kc = (tid & 7) << 4;
  const int swa = (ra & 7) << 3;
  const bf16x8* ap = reinterpret_cast<const bf16x8*>(Tbf + (size_t)(m0 + ra) * 512 + kc);

  const int bk8 = (lane >> 4) << 3;
  const u16* bp0 = Wcat + (size_t)(n0 + wn * 64 + (lane & 15)) * 512 + bk8;
  const u16* bp1 = bp0 + 16 * 512;
  const u16* bp2 = bp1 + 16 * 512;
  const u16* bp3 = bp2 + 16 * 512;

  const int arow0 = wm * 32 + (lane & 15);
  const int asw = (arow0 & 7) << 3;
  const int abase0 = arow0 * 128;
  const int abase1 = abase0 + 16 * 128;

  f32x4 acc[2][4];
  const f32x4 zf = {0.f, 0.f, 0.f, 0.f};
#pragma unroll
  for (int i = 0; i < 2; ++i)
#pragma unroll
    for (int j = 0; j < 4; ++j) acc[i][j] = zf;

  bf16x8 pA0, pA1, pB0, pB1;

  auto LOADA = [&](bf16x8& x0, bf16x8& x1, int s) {
    const bf16x8* p = ap + s * 16;
    x0 = p[0]; x1 = p[1];
  };
  auto STOREA = [&](u16* buf, bf16x8 x0, bf16x8 x1) {
    *reinterpret_cast<bf16x8*>(&buf[ra * 128 + (kc ^ swa)]) = x0;
    *reinterpret_cast<bf16x8*>(&buf[ra * 128 + ((kc + 8) ^ swa)]) = x1;
  };
  auto COMPUTE = [&](const u16* buf, int s) {
#pragma unroll
    for (int kk = 0; kk < 128; kk += 32) {
      bf16x8 b0 = *reinterpret_cast<const bf16x8*>(bp0 + s * 128 + kk);
      bf16x8 b1 = *reinterpret_cast<const bf16x8*>(bp1 + s * 128 + kk);
      bf16x8 b2 = *reinterpret_cast<const bf16x8*>(bp2 + s * 128 + kk);
      bf16x8 b3 = *reinterpret_cast<const bf16x8*>(bp3 + s * 128 + kk);
      const int ke = (kk + bk8) ^ asw;
      bf16x8 a0 = *reinterpret_cast<const bf16x8*>(&buf[abase0 + ke]);
      bf16x8 a1 = *reinterpret_cast<const bf16x8*>(&buf[abase1 + ke]);
      acc[0][0] = __builtin_amdgcn_mfma_f32_16x16x32_bf16(a0, b0, acc[0][0], 0, 0, 0);
      acc[0][1] = __builtin_amdgcn_mfma_f32_16x16x32_bf16(a0, b1, acc[0][1], 0, 0, 0);
      acc[0][2] = __builtin_amdgcn_mfma_f32_16x16x32_bf16(a0, b2, acc[0][2], 0, 0, 0);
      acc[0][3] = __builtin_amdgcn_mfma_f32_16x16x32_bf16(a0, b3, acc[0][3], 0, 0, 0);
      acc[1][0] = __builtin_amdgcn_mfma_f32_16x16x32_bf16(a1, b0, acc[1][0], 0, 0, 0);
      acc[1][1] = __builtin_amdgcn_mfma_f32_16x16x32_bf16(a1, b1, acc[1][1], 0, 0, 0);
      acc[1][2] = __builtin_amdgcn_mfma_f32_16x16x32_bf16(a1, b2, acc[1][2], 0, 0, 0);
      acc[1][3] = __builtin_amdgcn_mfma_f32_16x16x32_bf16(a1, b3, acc[1][3], 0, 0, 0);
    }
  };

  LOADA(pA0, pA1, 0);
  LOADA(pB0, pB1, 1);
  STOREA(As0, pA0, pA1);
  BARRIER();
#pragma unroll
  for (int s = 0; s < STEPS2; s += 2) {
    if (s + 2 < STEPS2) LOADA(pA0, pA1, s + 2);
    COMPUTE(As0, s);
    if (s + 1 < STEPS2) STOREA(As1, pB0, pB1);
    BARRIER();
    if (s + 3 < STEPS2) LOADA(pB0, pB1, s + 3);
    if (s + 1 < STEPS2) COMPUTE(As1, s + 1);
    if (s + 2 < STEPS2) STOREA(As0, pA0, pA1);
    BARRIER();
  }

  const int r0 = (lane >> 4) << 2;
  const int colw = n0 + wn * 64 + (lane & 15);
#pragma unroll
  for (int mi = 0; mi < 2; ++mi)
#pragma unroll
    for (int ni = 0; ni < 4; ++ni)
#pragma unroll
      for (int r = 0; r < 4; ++r)
        D[(size_t)(m0 + wm * 32 + mi * 16 + r0 + r) * NPAD + colw + ni * 16] = acc[mi][ni][r];
}

// ---------------------------------------------------------------- shift-sum + bias + relu + maxpool -> re[32][800]
__global__ __launch_bounds__(256) void reduce_conv(const float* __restrict__ D,
                                                   const float* __restrict__ b0,
                                                   const float* __restrict__ b1,
                                                   const float* __restrict__ b2,
                                                   const float* __restrict__ b3,
                                                   float* __restrict__ re) {
  __shared__ float tile[128][101];
  const int pair = blockIdx.y;
  const int sel = pair >> 5, b = pair & 31;
  const int kc = blockIdx.x;
  const int tid = threadIdx.x;
  const int rowbase = sel * (BB * LL) + b * LL;
  const int c0 = kc * 100;
  for (int idx = tid; idx < 12800; idx += 256) {
    int r = idx / 100, c = idx - r * 100;
    tile[r][c] = D[(size_t)(rowbase + r) * NPAD + c0 + c];
  }
  __syncthreads();
  const int wid = tid >> 6, lane = tid & 63;
  const int offt[4] = {0, 1, 3, 6};
  const int fst[4] = {1, 2, 3, 4};
  for (int o = wid; o < 40; o += 4) {
    const int kk = o >> 2, f = o & 3;
    const int fs = fst[f], off = offt[f];
    const int kg = kc * 10 + kk;
    const float bias = (f == 0 ? b0 : f == 1 ? b1 : f == 2 ? b2 : b3)[kg];
    const int col = kk * 10 + off;
    const int outh = 139 - fs;
    float best = 0.f;
    for (int i = lane; i < outh; i += 64) {
      float s = bias;
#pragma unroll 4
      for (int r = 0; r < 4; ++r) {
        if (r < fs) {
          int j = i + r - 5;
          if (j >= 0 && j < LL) s += tile[j][col + r];
        }
      }
      best = fmaxf(best, s);
    }
    best = fmaxf(best, 0.f);
#pragma unroll
    for (int d = 32; d; d >>= 1) best = fmaxf(best, __shfl_xor(best, d));
    if (lane == 0) re[(size_t)b * 800 + sel * 400 + f * 100 + kg] = best;
  }
}

// ---------------------------------------------------------------- dense + log_softmax -> out[32][2]
__global__ __launch_bounds__(64) void dense_logsm(const float* __restrict__ re,
                                                  const float* __restrict__ dw,
                                                  const float* __restrict__ db,
                                                  float* __restrict__ out) {
  const int b = blockIdx.x;
  const int lane = threadIdx.x;
  const float* r = re + (size_t)b * 800;
  float a0 = 0.f, a1 = 0.f;
  for (int j = lane; j < 800; j += 64) {
    float rv = r[j];
    a0 += rv * dw[j * 2];
    a1 += rv * dw[j * 2 + 1];
  }
#pragma unroll
  for (int d = 32; d; d >>= 1) {
    a0 += __shfl_xor(a0, d);
    a1 += __shfl_xor(a1, d);
  }
  if (lane == 0) {
    a0 += db[0];
    a1 += db[1];
    float mx = fmaxf(a0, a1);
    float lse = mx + logf(expf(a0 - mx) + expf(a1 - mx));
    out[b * 2] = a0 - lse;
    out[b * 2 + 1] = a1 - lse;
  }
}

// ---------------------------------------------------------------- workspace layout (bytes)
static const size_t OFF_PARTS = 0;                         // 8 * 8192*256 f32 = 67,108,864
static const size_t OFF_D     = 0;                         // alias (parts dead by conv time)
static const size_t OFF_Q     = 67108864;
static const size_t OFF_A     = OFF_Q + 4194304;
static const size_t OFF_SCORE = OFF_A + 4194304;
static const size_t OFF_WQ    = OFF_SCORE + 2097152;
static const size_t OFF_WAT   = OFF_WQ + 2097152;
static const size_t OFF_RE    = OFF_WAT + 2097152;
static const size_t OFF_TBF   = OFF_RE + 102400;
static const size_t OFF_WCAT  = OFF_TBF + 8388608;
static const size_t OFF_EMBT  = OFF_WCAT + 1048576;

extern "C" void kernel_launch(void* const* d_in, const int* in_sizes, int n_in,
                              void* d_out, int out_size, void* d_ws, size_t ws_size,
                              hipStream_t stream) {
  (void)in_sizes; (void)n_in; (void)out_size; (void)ws_size;
  const float* adj  = (const float*)d_in[0];
  const float* emb  = (const float*)d_in[1];
  const int* q_idx  = (const int*)d_in[2];
  const int* a_idx  = (const int*)d_in[3];
  const float* cw0 = (const float*)d_in[4];
  const float* cb0 = (const float*)d_in[5];
  const float* cw1 = (const float*)d_in[6];
  const float* cb1 = (const float*)d_in[7];
  const float* cw2 = (const float*)d_in[8];
  const float* cb2 = (const float*)d_in[9];
  const float* cw3 = (const float*)d_in[10];
  const float* cb3 = (const float*)d_in[11];
  const float* dw = (const float*)d_in[12];
  const float* db = (const float*)d_in[13];
  float* out = (float*)d_out;

  char* ws = (char*)d_ws;
  float* parts = (float*)(ws + OFF_PARTS);
  float* Dbuf  = (float*)(ws + OFF_D);
  float* Q     = (float*)(ws + OFF_Q);
  float* Abuf  = (float*)(ws + OFF_A);
  float* score = (float*)(ws + OFF_SCORE);
  float* wq    = (float*)(ws + OFF_WQ);
  float* waT   = (float*)(ws + OFF_WAT);
  float* re    = (float*)(ws + OFF_RE);
  u16* Tbf     = (u16*)(ws + OFF_TBF);
  u16* Wcat    = (u16*)(ws + OFF_WCAT);
  u16* embT    = (u16*)(ws + OFF_EMBT);

  convert_embT<<<dim3(128, 4), 256, 0, stream>>>(emb, embT);
  prep_wcat<<<1024, 256, 0, stream>>>(cw0, cw1, cw2, cw3, Wcat);
  gemm_layer1<<<dim3(64, SPLITK), 1024, 0, stream>>>(adj, embT, parts);
  gather_qa<<<2 * BB * LL, 256, 0, stream>>>(parts, q_idx, a_idx, Q, Abuf);
  score_row<<<BB * LL, 128, 0, stream>>>(Q, Abuf, score, wq);
  softmax_col<<<BB * LL, 64, 0, stream>>>(score, waT);
  align_encode<<<256, 1024, 0, stream>>>(wq, waT, Q, Abuf, Tbf);
  gemm_conv<<<dim3(64, 4), 1024, 0, stream>>>(Tbf, Wcat, Dbuf);
  reduce_conv<<<dim3(10, 64), 256, 0, stream>>>(Dbuf, cb0, cb1, cb2, cb3, re);
  dense_logsm<<<BB, 64, 0, stream>>>(re, dw, db, out);
}

// Round 5
// 252.963 us; speedup vs baseline: 1.3502x; 1.3502x over previous
//
#include <hip/hip_runtime.h>
#include <hip/hip_bf16.h>
#include <stdint.h>

typedef unsigned short u16;
typedef __attribute__((ext_vector_type(8))) short bf16x8;
typedef __attribute__((ext_vector_type(4))) float f32x4;

#define NN 8192
#define HH 256
#define KK 100
#define BB 32
#define LL 128
#define NPAD 1024
#define SPLITK 4
#define KCH (NN / SPLITK)   // 2048
#define STEPS1 (KCH / 64)   // 32
#define STEPS2 (512 / 64)   // 8

// raw barrier: waits LDS ops only; prefetch global loads stay in flight
#define BARRIER() asm volatile("s_waitcnt lgkmcnt(0)\ns_barrier" ::: "memory")

__device__ __forceinline__ u16 f2bf_rne(float x) {
  union { __hip_bfloat16 h; u16 u; } v;
  v.h = __float2bfloat16(x);
  return v.u;
}

__device__ __forceinline__ bf16x8 pack8(f32x4 a, f32x4 b) {
  bf16x8 r;
  r[0] = (short)f2bf_rne(a.x); r[1] = (short)f2bf_rne(a.y);
  r[2] = (short)f2bf_rne(a.z); r[3] = (short)f2bf_rne(a.w);
  r[4] = (short)f2bf_rne(b.x); r[5] = (short)f2bf_rne(b.y);
  r[6] = (short)f2bf_rne(b.z); r[7] = (short)f2bf_rne(b.w);
  return r;
}

// ---------------------------------------------------------------- embT: [256][8192] bf16 = emb^T
__global__ __launch_bounds__(256) void convert_embT(const float* __restrict__ emb,
                                                    u16* __restrict__ embT) {
  __shared__ float t[64][65];
  const int tid = threadIdx.x;
  const int k0 = blockIdx.x * 64, n0 = blockIdx.y * 64;
#pragma unroll
  for (int i = 0; i < 16; ++i) {
    int idx = i * 256 + tid;
    int r = idx >> 6, c = idx & 63;
    t[r][c] = emb[(size_t)(k0 + r) * HH + n0 + c];
  }
  __syncthreads();
#pragma unroll
  for (int i = 0; i < 16; ++i) {
    int idx = i * 256 + tid;
    int r = idx >> 6, c = idx & 63;
    embT[(size_t)(n0 + r) * NN + k0 + c] = f2bf_rne(t[c][r]);
  }
}

// ---------------------------------------------------------------- layer1 = adj @ emb (bf16 MFMA)
// BM=128, BN=256(all H), BK=64, 512 thr (8 waves 2Mx4N), split-K=4, grid (64,4).
// 2-phase: issue loads(t+1) -> COMPUTE(t) -> cvt+ds_write(t+1) -> lgkm barrier.
__global__ __launch_bounds__(512, 2) void gemm_layer1(const float* __restrict__ adj,
                                                      const u16* __restrict__ embT,
                                                      float* __restrict__ parts) {
  __shared__ __align__(16) u16 As[2][128 * 64];
  __shared__ __align__(16) u16 Bs[2][256 * 64];
  const int tid = threadIdx.x;
  const int lane = tid & 63, wid = tid >> 6;
  const int wm = wid >> 2, wn = wid & 3;
  const int m0 = blockIdx.x * 128;
  const int kbeg = blockIdx.y * KCH;

  // A staging map: row ra, 16 consecutive k at kc
  const int ra = tid >> 2;
  const int kc = (tid & 3) << 4;
  const int swa = (ra & 7) << 3;
  const f32x4* ap = reinterpret_cast<const f32x4*>(adj + (size_t)(m0 + ra) * NN + kbeg + kc);

  // B staging map: 4 chunks of 8 bf16 per thread
  int brow[4], bko[4];
  const u16* bptr[4];
#pragma unroll
  for (int i = 0; i < 4; ++i) {
    int c = i * 512 + tid;
    brow[i] = c >> 3;
    bko[i] = (c & 7) << 3;
    bptr[i] = embT + (size_t)brow[i] * NN + kbeg + bko[i];
  }

  f32x4 acc[4][4];
  const f32x4 zf = {0.f, 0.f, 0.f, 0.f};
#pragma unroll
  for (int i = 0; i < 4; ++i)
#pragma unroll
    for (int j = 0; j < 4; ++j) acc[i][j] = zf;

  f32x4 av0, av1, av2, av3;
  bf16x8 bv0, bv1, bv2, bv3;

  auto LOAD = [&](int s) {
    const f32x4* p = ap + s * 16;
    av0 = __builtin_nontemporal_load(p);
    av1 = __builtin_nontemporal_load(p + 1);
    av2 = __builtin_nontemporal_load(p + 2);
    av3 = __builtin_nontemporal_load(p + 3);
    bv0 = *reinterpret_cast<const bf16x8*>(bptr[0] + s * 64);
    bv1 = *reinterpret_cast<const bf16x8*>(bptr[1] + s * 64);
    bv2 = *reinterpret_cast<const bf16x8*>(bptr[2] + s * 64);
    bv3 = *reinterpret_cast<const bf16x8*>(bptr[3] + s * 64);
  };
  auto STORE = [&](int buf) {
    *reinterpret_cast<bf16x8*>(&As[buf][ra * 64 + (kc ^ swa)]) = pack8(av0, av1);
    *reinterpret_cast<bf16x8*>(&As[buf][ra * 64 + ((kc + 8) ^ swa)]) = pack8(av2, av3);
    *reinterpret_cast<bf16x8*>(&Bs[buf][brow[0] * 64 + (bko[0] ^ ((brow[0] & 7) << 3))]) = bv0;
    *reinterpret_cast<bf16x8*>(&Bs[buf][brow[1] * 64 + (bko[1] ^ ((brow[1] & 7) << 3))]) = bv1;
    *reinterpret_cast<bf16x8*>(&Bs[buf][brow[2] * 64 + (bko[2] ^ ((brow[2] & 7) << 3))]) = bv2;
    *reinterpret_cast<bf16x8*>(&Bs[buf][brow[3] * 64 + (bko[3] ^ ((brow[3] & 7) << 3))]) = bv3;
  };
  auto COMPUTE = [&](int buf) {
#pragma unroll
    for (int kk = 0; kk < 64; kk += 32) {
      const int krow = kk + ((lane >> 4) << 3);
      bf16x8 af[4], bfr[4];
#pragma unroll
      for (int mi = 0; mi < 4; ++mi) {
        int row = wm * 64 + mi * 16 + (lane & 15);
        af[mi] = *reinterpret_cast<const bf16x8*>(&As[buf][row * 64 + (krow ^ ((row & 7) << 3))]);
      }
#pragma unroll
      for (int ni = 0; ni < 4; ++ni) {
        int row = wn * 64 + ni * 16 + (lane & 15);
        bfr[ni] = *reinterpret_cast<const bf16x8*>(&Bs[buf][row * 64 + (krow ^ ((row & 7) << 3))]);
      }
#pragma unroll
      for (int mi = 0; mi < 4; ++mi)
#pragma unroll
        for (int ni = 0; ni < 4; ++ni)
          acc[mi][ni] = __builtin_amdgcn_mfma_f32_16x16x32_bf16(af[mi], bfr[ni], acc[mi][ni], 0, 0, 0);
    }
  };

  LOAD(0);
  STORE(0);
  BARRIER();
  int cur = 0;
  for (int s = 0; s < STEPS1; ++s) {
    if (s + 1 < STEPS1) LOAD(s + 1);
    COMPUTE(cur);
    if (s + 1 < STEPS1) STORE(cur ^ 1);
    BARRIER();
    cur ^= 1;
  }

  float* outp = parts + (size_t)blockIdx.y * ((size_t)NN * HH);
  const int r0 = (lane >> 4) << 2;
  const int coln = wn * 64 + (lane & 15);
#pragma unroll
  for (int mi = 0; mi < 4; ++mi)
#pragma unroll
    for (int ni = 0; ni < 4; ++ni)
#pragma unroll
      for (int r = 0; r < 4; ++r)
        outp[(size_t)(m0 + wm * 64 + mi * 16 + r0 + r) * HH + coln + ni * 16] = acc[mi][ni][r];
}

// ---------------------------------------------------------------- gather: Q/A rows = sum of split-K parts
__global__ __launch_bounds__(256) void gather_qa(const float* __restrict__ parts,
                                                 const int* __restrict__ q_idx,
                                                 const int* __restrict__ a_idx,
                                                 float* __restrict__ Q, float* __restrict__ A) {
  const int rb = blockIdx.x;
  const bool isA = rb >= BB * LL;
  const int r = isA ? rb - BB * LL : rb;
  const int idx = (isA ? a_idx : q_idx)[r];
  const int tid = threadIdx.x;
  float s = 0.f;
#pragma unroll
  for (int p = 0; p < SPLITK; ++p)
    s += parts[(size_t)p * ((size_t)NN * HH) + (size_t)idx * HH + tid];
  (isA ? A : Q)[(size_t)r * HH + tid] = s;
}

// ---------------------------------------------------------------- score + row softmax fused
__global__ __launch_bounds__(128) void score_row(const float* __restrict__ Q,
                                                 const float* __restrict__ A,
                                                 float* __restrict__ score,
                                                 float* __restrict__ wq) {
  __shared__ float qs[HH];
  __shared__ float red[4];
  const int bl = blockIdx.x;
  const int b = bl >> 7;
  const int tid = threadIdx.x;
  const int wv = tid >> 6, lane = tid & 63;
  qs[tid] = Q[(size_t)bl * HH + tid];
  qs[tid + 128] = Q[(size_t)bl * HH + tid + 128];
  __syncthreads();
  const float4* a4 = reinterpret_cast<const float4*>(A + ((size_t)b * LL + tid) * HH);
  const float4* q4 = reinterpret_cast<const float4*>(qs);
  float acc = 0.f;
#pragma unroll 8
  for (int h = 0; h < HH / 4; ++h) {
    float4 av = a4[h], qv = q4[h];
    acc += av.x * qv.x + av.y * qv.y + av.z * qv.z + av.w * qv.w;
  }
  float mx = acc;
#pragma unroll
  for (int off = 32; off; off >>= 1) mx = fmaxf(mx, __shfl_xor(mx, off));
  if (lane == 0) red[wv] = mx;
  __syncthreads();
  mx = fmaxf(red[0], red[1]);
  float e = expf(acc - mx);
  float sm = e;
#pragma unroll
  for (int off = 32; off; off >>= 1) sm += __shfl_xor(sm, off);
  if (lane == 0) red[2 + wv] = sm;
  __syncthreads();
  sm = red[2] + red[3];
  score[(size_t)bl * LL + tid] = acc;
  wq[(size_t)bl * LL + tid] = e / sm;
}

// ---------------------------------------------------------------- softmax over l (cols) -> waT[b][m][l]
__global__ __launch_bounds__(64) void softmax_col(const float* __restrict__ score,
                                                  float* __restrict__ waT) {
  const int bm = blockIdx.x;
  const int b = bm >> 7, m = bm & 127;
  const int lane = threadIdx.x;
  const float* s = score + (size_t)b * LL * LL + m;
  float x0 = s[(size_t)lane * LL], x1 = s[(size_t)(lane + 64) * LL];
  float mx = fmaxf(x0, x1);
#pragma unroll
  for (int off = 32; off; off >>= 1) mx = fmaxf(mx, __shfl_xor(mx, off));
  float e0 = expf(x0 - mx), e1 = expf(x1 - mx);
  float sum = e0 + e1;
#pragma unroll
  for (int off = 32; off; off >>= 1) sum += __shfl_xor(sum, off);
  float inv = 1.f / sum;
  waT[(size_t)bm * LL + lane] = e0 * inv;
  waT[(size_t)bm * LL + lane + 64] = e1 * inv;
}

// ---------------------------------------------------------------- align+encode: EQ/EA + match features -> Tbf
__global__ __launch_bounds__(1024) void align_encode(const float* __restrict__ wq,
                                                     const float* __restrict__ waT,
                                                     const float* __restrict__ Q,
                                                     const float* __restrict__ A,
                                                     u16* __restrict__ Tbf) {
  __shared__ float wl[128 * 128];
  __shared__ float sl[128 * 64];
  const int bid = blockIdx.x;
  const int side = bid >> 7;
  const int b = (bid >> 2) & 31;
  const int h0 = (bid & 3) * 64;
  const int tid = threadIdx.x;
  const int lt = tid >> 6, hx = tid & 63;

  const float* wsrc = (side ? waT : wq) + (size_t)b * (LL * LL);
  const float* ssrc = (side ? Q : A) + (size_t)b * (LL * HH) + h0;
  const float* msrc = (side ? A : Q) + (size_t)b * (LL * HH) + h0;

#pragma unroll
  for (int i = 0; i < 16; ++i) {
    int idx = i * 1024 + tid;
    wl[idx] = wsrc[idx];
  }
#pragma unroll
  for (int i = 0; i < 8; ++i) {
    int idx = i * 1024 + tid;
    int r = idx >> 6, c = idx & 63;
    sl[idx] = ssrc[(size_t)r * HH + c];
  }
  __syncthreads();

  float accv[8];
#pragma unroll
  for (int ii = 0; ii < 8; ++ii) accv[ii] = 0.f;

  for (int j4 = 0; j4 < 128; j4 += 4) {
    float s0 = sl[(j4 + 0) * 64 + hx];
    float s1 = sl[(j4 + 1) * 64 + hx];
    float s2 = sl[(j4 + 2) * 64 + hx];
    float s3 = sl[(j4 + 3) * 64 + hx];
#pragma unroll
    for (int ii = 0; ii < 8; ++ii) {
      float4 wv = *reinterpret_cast<const float4*>(&wl[(lt + 16 * ii) * 128 + j4]);
      accv[ii] += wv.x * s0 + wv.y * s1 + wv.z * s2 + wv.w * s3;
    }
  }

  u16* outp = Tbf + (size_t)(side * 4096 + b * 128) * 512 + h0;
#pragma unroll
  for (int ii = 0; ii < 8; ++ii) {
    int i = lt + 16 * ii;
    float mv = msrc[(size_t)i * HH + hx];
    float e = accv[ii];
    float d = mv - e;
    outp[(size_t)i * 512 + hx] = f2bf_rne(d * d);
    outp[(size_t)i * 512 + 256 + hx] = f2bf_rne(mv * e);
  }
}

// ---------------------------------------------------------------- Wcat bf16 [1024][512]
__global__ __launch_bounds__(256) void prep_wcat(const float* __restrict__ w0,
                                                 const float* __restrict__ w1,
                                                 const float* __restrict__ w2,
                                                 const float* __restrict__ w3,
                                                 u16* __restrict__ Wcat) {
  const int kr = blockIdx.x;
  const int tid = threadIdx.x;
  u16* out = Wcat + (size_t)kr * 512;
  if (kr >= KK * 10) {
    out[tid] = 0;
    out[tid + 256] = 0;
    return;
  }
  const int k = kr / 10, s = kr % 10;
  const float* w;
  int r, fs;
  if (s < 1)      { w = w0; r = s;     fs = 1; }
  else if (s < 3) { w = w1; r = s - 1; fs = 2; }
  else if (s < 6) { w = w2; r = s - 3; fs = 3; }
  else            { w = w3; r = s - 6; fs = 4; }
  const float* src = w + ((size_t)k * fs + r) * 522 + 5;
  out[tid] = f2bf_rne(src[tid]);
  out[tid + 256] = f2bf_rne(src[tid + 256]);
}

// ---------------------------------------------------------------- conv GEMM: D[8192][1024] = Tbf @ Wcat^T
// Same 2-phase skeleton; A bf16 (no convert). grid (64,4).
__global__ __launch_bounds__(512, 2) void gemm_conv(const u16* __restrict__ Tbf,
                                                    const u16* __restrict__ Wcat,
                                                    float* __restrict__ D) {
  __shared__ __align__(16) u16 As[2][128 * 64];
  __shared__ __align__(16) u16 Bs[2][256 * 64];
  const int tid = threadIdx.x;
  const int lane = tid & 63, wid = tid >> 6;
  const int wm = wid >> 2, wn = wid & 3;
  const int m0 = blockIdx.x * 128;
  const int n0 = blockIdx.y * 256;

  const int ra = tid >> 2;
  const int kc = (tid & 3) << 4;
  const int swa = (ra & 7) << 3;
  const bf16x8* ap = reinterpret_cast<const bf16x8*>(Tbf + (size_t)(m0 + ra) * 512 + kc);

  int brow[4], bko[4];
  const u16* bptr[4];
#pragma unroll
  for (int i = 0; i < 4; ++i) {
    int c = i * 512 + tid;
    brow[i] = c >> 3;
    bko[i] = (c & 7) << 3;
    bptr[i] = Wcat + (size_t)(n0 + brow[i]) * 512 + bko[i];
  }

  f32x4 acc[4][4];
  const f32x4 zf = {0.f, 0.f, 0.f, 0.f};
#pragma unroll
  for (int i = 0; i < 4; ++i)
#pragma unroll
    for (int j = 0; j < 4; ++j) acc[i][j] = zf;

  bf16x8 av0, av1, bv0, bv1, bv2, bv3;

  auto LOAD = [&](int s) {
    const bf16x8* p = ap + s * 8;
    av0 = p[0];
    av1 = p[1];
    bv0 = *reinterpret_cast<const bf16x8*>(bptr[0] + s * 64);
    bv1 = *reinterpret_cast<const bf16x8*>(bptr[1] + s * 64);
    bv2 = *reinterpret_cast<const bf16x8*>(bptr[2] + s * 64);
    bv3 = *reinterpret_cast<const bf16x8*>(bptr[3] + s * 64);
  };
  auto STORE = [&](int buf) {
    *reinterpret_cast<bf16x8*>(&As[buf][ra * 64 + (kc ^ swa)]) = av0;
    *reinterpret_cast<bf16x8*>(&As[buf][ra * 64 + ((kc + 8) ^ swa)]) = av1;
    *reinterpret_cast<bf16x8*>(&Bs[buf][brow[0] * 64 + (bko[0] ^ ((brow[0] & 7) << 3))]) = bv0;
    *reinterpret_cast<bf16x8*>(&Bs[buf][brow[1] * 64 + (bko[1] ^ ((brow[1] & 7) << 3))]) = bv1;
    *reinterpret_cast<bf16x8*>(&Bs[buf][brow[2] * 64 + (bko[2] ^ ((brow[2] & 7) << 3))]) = bv2;
    *reinterpret_cast<bf16x8*>(&Bs[buf][brow[3] * 64 + (bko[3] ^ ((brow[3] & 7) << 3))]) = bv3;
  };
  auto COMPUTE = [&](int buf) {
#pragma unroll
    for (int kk = 0; kk < 64; kk += 32) {
      const int krow = kk + ((lane >> 4) << 3);
      bf16x8 af[4], bfr[4];
#pragma unroll
      for (int mi = 0; mi < 4; ++mi) {
        int row = wm * 64 + mi * 16 + (lane & 15);
        af[mi] = *reinterpret_cast<const bf16x8*>(&As[buf][row * 64 + (krow ^ ((row & 7) << 3))]);
      }
#pragma unroll
      for (int ni = 0; ni < 4; ++ni) {
        int row = wn * 64 + ni * 16 + (lane & 15);
        bfr[ni] = *reinterpret_cast<const bf16x8*>(&Bs[buf][row * 64 + (krow ^ ((row & 7) << 3))]);
      }
#pragma unroll
      for (int mi = 0; mi < 4; ++mi)
#pragma unroll
        for (int ni = 0; ni < 4; ++ni)
          acc[mi][ni] = __builtin_amdgcn_mfma_f32_16x16x32_bf16(af[mi], bfr[ni], acc[mi][ni], 0, 0, 0);
    }
  };

  LOAD(0);
  STORE(0);
  BARRIER();
  int cur = 0;
  for (int s = 0; s < STEPS2; ++s) {
    if (s + 1 < STEPS2) LOAD(s + 1);
    COMPUTE(cur);
    if (s + 1 < STEPS2) STORE(cur ^ 1);
    BARRIER();
    cur ^= 1;
  }

  const int r0 = (lane >> 4) << 2;
  const int coln = n0 + wn * 64 + (lane & 15);
#pragma unroll
  for (int mi = 0; mi < 4; ++mi)
#pragma unroll
    for (int ni = 0; ni < 4; ++ni)
#pragma unroll
      for (int r = 0; r < 4; ++r)
        D[(size_t)(m0 + wm * 64 + mi * 16 + r0 + r) * NPAD + coln + ni * 16] = acc[mi][ni][r];
}

// ---------------------------------------------------------------- shift-sum + bias + relu + maxpool -> re[32][800]
__global__ __launch_bounds__(256) void reduce_conv(const float* __restrict__ D,
                                                   const float* __restrict__ b0,
                                                   const float* __restrict__ b1,
                                                   const float* __restrict__ b2,
                                                   const float* __restrict__ b3,
                                                   float* __restrict__ re) {
  __shared__ float tile[128][101];
  const int pair = blockIdx.y;
  const int sel = pair >> 5, b = pair & 31;
  const int kc = blockIdx.x;
  const int tid = threadIdx.x;
  const int rowbase = sel * (BB * LL) + b * LL;
  const int c0 = kc * 100;
  for (int idx = tid; idx < 12800; idx += 256) {
    int r = idx / 100, c = idx - r * 100;
    tile[r][c] = D[(size_t)(rowbase + r) * NPAD + c0 + c];
  }
  __syncthreads();
  const int wid = tid >> 6, lane = tid & 63;
  const int offt[4] = {0, 1, 3, 6};
  const int fst[4] = {1, 2, 3, 4};
  for (int o = wid; o < 40; o += 4) {
    const int kk = o >> 2, f = o & 3;
    const int fs = fst[f], off = offt[f];
    const int kg = kc * 10 + kk;
    const float bias = (f == 0 ? b0 : f == 1 ? b1 : f == 2 ? b2 : b3)[kg];
    const int col = kk * 10 + off;
    const int outh = 139 - fs;
    float best = 0.f;
    for (int i = lane; i < outh; i += 64) {
      float s = bias;
#pragma unroll 4
      for (int r = 0; r < 4; ++r) {
        if (r < fs) {
          int j = i + r - 5;
          if (j >= 0 && j < LL) s += tile[j][col + r];
        }
      }
      best = fmaxf(best, s);
    }
    best = fmaxf(best, 0.f);
#pragma unroll
    for (int d = 32; d; d >>= 1) best = fmaxf(best, __shfl_xor(best, d));
    if (lane == 0) re[(size_t)b * 800 + sel * 400 + f * 100 + kg] = best;
  }
}

// ---------------------------------------------------------------- dense + log_softmax -> out[32][2]
__global__ __launch_bounds__(64) void dense_logsm(const float* __restrict__ re,
                                                  const float* __restrict__ dw,
                                                  const float* __restrict__ db,
                                                  float* __restrict__ out) {
  const int b = blockIdx.x;
  const int lane = threadIdx.x;
  const float* r = re + (size_t)b * 800;
  float a0 = 0.f, a1 = 0.f;
  for (int j = lane; j < 800; j += 64) {
    float rv = r[j];
    a0 += rv * dw[j * 2];
    a1 += rv * dw[j * 2 + 1];
  }
#pragma unroll
  for (int d = 32; d; d >>= 1) {
    a0 += __shfl_xor(a0, d);
    a1 += __shfl_xor(a1, d);
  }
  if (lane == 0) {
    a0 += db[0];
    a1 += db[1];
    float mx = fmaxf(a0, a1);
    float lse = mx + logf(expf(a0 - mx) + expf(a1 - mx));
    out[b * 2] = a0 - lse;
    out[b * 2 + 1] = a1 - lse;
  }
}

// ---------------------------------------------------------------- workspace layout (bytes)
static const size_t OFF_PARTS = 0;                         // 4 * 8192*256 f32 = 33,554,432 (region reserves 64MB)
static const size_t OFF_D     = 0;                         // alias (parts dead by conv time)
static const size_t OFF_Q     = 67108864;
static const size_t OFF_A     = OFF_Q + 4194304;
static const size_t OFF_SCORE = OFF_A + 4194304;
static const size_t OFF_WQ    = OFF_SCORE + 2097152;
static const size_t OFF_WAT   = OFF_WQ + 2097152;
static const size_t OFF_RE    = OFF_WAT + 2097152;
static const size_t OFF_TBF   = OFF_RE + 102400;
static const size_t OFF_WCAT  = OFF_TBF + 8388608;
static const size_t OFF_EMBT  = OFF_WCAT + 1048576;

extern "C" void kernel_launch(void* const* d_in, const int* in_sizes, int n_in,
                              void* d_out, int out_size, void* d_ws, size_t ws_size,
                              hipStream_t stream) {
  (void)in_sizes; (void)n_in; (void)out_size; (void)ws_size;
  const float* adj  = (const float*)d_in[0];
  const float* emb  = (const float*)d_in[1];
  const int* q_idx  = (const int*)d_in[2];
  const int* a_idx  = (const int*)d_in[3];
  const float* cw0 = (const float*)d_in[4];
  const float* cb0 = (const float*)d_in[5];
  const float* cw1 = (const float*)d_in[6];
  const float* cb1 = (const float*)d_in[7];
  const float* cw2 = (const float*)d_in[8];
  const float* cb2 = (const float*)d_in[9];
  const float* cw3 = (const float*)d_in[10];
  const float* cb3 = (const float*)d_in[11];
  const float* dw = (const float*)d_in[12];
  const float* db = (const float*)d_in[13];
  float* out = (float*)d_out;

  char* ws = (char*)d_ws;
  float* parts = (float*)(ws + OFF_PARTS);
  float* Dbuf  = (float*)(ws + OFF_D);
  float* Q     = (float*)(ws + OFF_Q);
  float* Abuf  = (float*)(ws + OFF_A);
  float* score = (float*)(ws + OFF_SCORE);
  float* wq    = (float*)(ws + OFF_WQ);
  float* waT   = (float*)(ws + OFF_WAT);
  float* re    = (float*)(ws + OFF_RE);
  u16* Tbf     = (u16*)(ws + OFF_TBF);
  u16* Wcat    = (u16*)(ws + OFF_WCAT);
  u16* embT    = (u16*)(ws + OFF_EMBT);

  convert_embT<<<dim3(128, 4), 256, 0, stream>>>(emb, embT);
  prep_wcat<<<1024, 256, 0, stream>>>(cw0, cw1, cw2, cw3, Wcat);
  gemm_layer1<<<dim3(64, SPLITK), 512, 0, stream>>>(adj, embT, parts);
  gather_qa<<<2 * BB * LL, 256, 0, stream>>>(parts, q_idx, a_idx, Q, Abuf);
  score_row<<<BB * LL, 128, 0, stream>>>(Q, Abuf, score, wq);
  softmax_col<<<BB * LL, 64, 0, stream>>>(score, waT);
  align_encode<<<256, 1024, 0, stream>>>(wq, waT, Q, Abuf, Tbf);
  gemm_conv<<<dim3(64, 4), 512, 0, stream>>>(Tbf, Wcat, Dbuf);
  reduce_conv<<<dim3(10, 64), 256, 0, stream>>>(Dbuf, cb0, cb1, cb2, cb3, re);
  dense_logsm<<<BB, 64, 0, stream>>>(re, dw, db, out);
}

// Round 6
// 241.485 us; speedup vs baseline: 1.4144x; 1.0475x over previous
//
#include <hip/hip_runtime.h>
#include <hip/hip_bf16.h>
#include <stdint.h>

typedef unsigned short u16;
typedef __attribute__((ext_vector_type(8))) short bf16x8;
typedef __attribute__((ext_vector_type(4))) float f32x4;

#define NN 8192
#define HH 256
#define KK 100
#define BB 32
#define LL 128
#define NPAD 1024
#define SPLITK 8
#define KCH (NN / SPLITK)   // 1024
#define STEPS1 (KCH / 64)   // 16
#define STEPS2 (512 / 64)   // 8

__device__ __forceinline__ u16 f2bf_rne(float x) {
  union { __hip_bfloat16 h; u16 u; } v;
  v.h = __float2bfloat16(x);
  return v.u;
}

__device__ __forceinline__ bf16x8 pack8(f32x4 a, f32x4 b) {
  bf16x8 r;
  r[0] = (short)f2bf_rne(a.x); r[1] = (short)f2bf_rne(a.y);
  r[2] = (short)f2bf_rne(a.z); r[3] = (short)f2bf_rne(a.w);
  r[4] = (short)f2bf_rne(b.x); r[5] = (short)f2bf_rne(b.y);
  r[6] = (short)f2bf_rne(b.z); r[7] = (short)f2bf_rne(b.w);
  return r;
}

// async global->LDS, 16B per lane. LDS dest is wave-uniform base + lane*16.
__device__ __forceinline__ void gld16(const void* g, void* l) {
  __builtin_amdgcn_global_load_lds(
      (const __attribute__((address_space(1))) unsigned int*)g,
      (__attribute__((address_space(3))) unsigned int*)l, 16, 0, 0);
}

// ---------------------------------------------------------------- embT: [256][8192] bf16 = emb^T
__global__ __launch_bounds__(256) void convert_embT(const float* __restrict__ emb,
                                                    u16* __restrict__ embT) {
  __shared__ float t[64][65];
  const int tid = threadIdx.x;
  const int k0 = blockIdx.x * 64, n0 = blockIdx.y * 64;
#pragma unroll
  for (int i = 0; i < 16; ++i) {
    int idx = i * 256 + tid;
    int r = idx >> 6, c = idx & 63;
    t[r][c] = emb[(size_t)(k0 + r) * HH + n0 + c];
  }
  __syncthreads();
#pragma unroll
  for (int i = 0; i < 16; ++i) {
    int idx = i * 256 + tid;
    int r = idx >> 6, c = idx & 63;
    embT[(size_t)(n0 + r) * NN + k0 + c] = f2bf_rne(t[c][r]);
  }
}

// ---------------------------------------------------------------- layer1 = adj @ emb (bf16 MFMA)
// m97 structure: global_load_lds staging, single-buffered, __syncthreads drains.
// BM=128, BN=256(all H), BK=64, 512 thr (8 waves 2Mx4N), split-K=8.
// Flat grid 512; sk = wg&7 -> XCD gets one k-slice (B slice L2-resident).
// A kept fp32 in LDS; converted to bf16 at fragment read.
__global__ __launch_bounds__(512, 4) void gemm_layer1(const float* __restrict__ adj,
                                                      const u16* __restrict__ embT,
                                                      float* __restrict__ parts) {
  __shared__ __align__(16) float As[128 * 64];  // 32 KB, swizzled
  __shared__ __align__(16) u16 Bs[256 * 64];    // 32 KB, swizzled
  const int tid = threadIdx.x;
  const int lane = tid & 63, wid = tid >> 6;
  const int wm = wid >> 2, wn = wid & 3;
  const int wg = blockIdx.x;
  const int sk = wg & 7;        // split-K slice == XCD (round-robin dispatch)
  const int m0 = (wg >> 3) * 128;
  const int kbeg = sk * KCH;

  f32x4 acc[4][4];
  const f32x4 zf = {0.f, 0.f, 0.f, 0.f};
#pragma unroll
  for (int i = 0; i < 4; ++i)
#pragma unroll
    for (int j = 0; j < 4; ++j) acc[i][j] = zf;

  // pre-swizzled global source columns (rule #21: linear LDS dest, swizzled src, swizzled read)
  const int arowL = (lane >> 4);            // row-within-1KB for A instr
  const int akL = (lane & 15) << 2;         // float slot
  const int browL = (lane >> 3);
  const int bkL = (lane & 7) << 3;          // bf16 slot

  for (int s = 0; s < STEPS1; ++s) {
    const int ks = kbeg + s * 64;
#pragma unroll
    for (int j = 0; j < 4; ++j) {
      // A: instr covers rows wid*16+j*4 .. +3 (1 KB)
      int rowA = (wid << 4) + (j << 2) + arowL;
      int kA = akL ^ ((rowA & 7) << 3);
      gld16(adj + (size_t)(m0 + rowA) * NN + ks + kA, (void*)&As[(wid * 4 + j) * 256]);
      // B: instr covers rows wid*32+j*8 .. +7 (1 KB)
      int rowB = (wid << 5) + (j << 3) + browL;
      int kB = bkL ^ ((rowB & 7) << 3);
      gld16(embT + (size_t)rowB * NN + ks + kB, (void*)&Bs[(wid * 4 + j) * 512]);
    }
    __syncthreads();   // drains vmcnt; 2 blocks/CU overlap each other's drain
#pragma unroll
    for (int kk = 0; kk < 64; kk += 32) {
      const int krow = kk + ((lane >> 4) << 3);
      bf16x8 af[4], bfr[4];
#pragma unroll
      for (int mi = 0; mi < 4; ++mi) {
        int row = wm * 64 + mi * 16 + (lane & 15);
        const f32x4* p = reinterpret_cast<const f32x4*>(&As[row * 64 + (krow ^ ((row & 7) << 3))]);
        af[mi] = pack8(p[0], p[1]);
      }
#pragma unroll
      for (int ni = 0; ni < 4; ++ni) {
        int row = wn * 64 + ni * 16 + (lane & 15);
        bfr[ni] = *reinterpret_cast<const bf16x8*>(&Bs[row * 64 + (krow ^ ((row & 7) << 3))]);
      }
#pragma unroll
      for (int mi = 0; mi < 4; ++mi)
#pragma unroll
        for (int ni = 0; ni < 4; ++ni)
          acc[mi][ni] = __builtin_amdgcn_mfma_f32_16x16x32_bf16(af[mi], bfr[ni], acc[mi][ni], 0, 0, 0);
    }
    __syncthreads();   // protect LDS reuse
  }

  float* outp = parts + (size_t)sk * ((size_t)NN * HH);
  const int r0 = (lane >> 4) << 2;
  const int coln = wn * 64 + (lane & 15);
#pragma unroll
  for (int mi = 0; mi < 4; ++mi)
#pragma unroll
    for (int ni = 0; ni < 4; ++ni)
#pragma unroll
      for (int r = 0; r < 4; ++r)
        outp[(size_t)(m0 + wm * 64 + mi * 16 + r0 + r) * HH + coln + ni * 16] = acc[mi][ni][r];
}

// ---------------------------------------------------------------- gather: Q/A rows = sum of split-K parts
__global__ __launch_bounds__(256) void gather_qa(const float* __restrict__ parts,
                                                 const int* __restrict__ q_idx,
                                                 const int* __restrict__ a_idx,
                                                 float* __restrict__ Q, float* __restrict__ A) {
  const int rb = blockIdx.x;
  const bool isA = rb >= BB * LL;
  const int r = isA ? rb - BB * LL : rb;
  const int idx = (isA ? a_idx : q_idx)[r];
  const int tid = threadIdx.x;
  float s = 0.f;
#pragma unroll
  for (int p = 0; p < SPLITK; ++p)
    s += parts[(size_t)p * ((size_t)NN * HH) + (size_t)idx * HH + tid];
  (isA ? A : Q)[(size_t)r * HH + tid] = s;
}

// ---------------------------------------------------------------- score + row softmax fused
__global__ __launch_bounds__(128) void score_row(const float* __restrict__ Q,
                                                 const float* __restrict__ A,
                                                 float* __restrict__ score,
                                                 float* __restrict__ wq) {
  __shared__ float qs[HH];
  __shared__ float red[4];
  const int bl = blockIdx.x;
  const int b = bl >> 7;
  const int tid = threadIdx.x;
  const int wv = tid >> 6, lane = tid & 63;
  qs[tid] = Q[(size_t)bl * HH + tid];
  qs[tid + 128] = Q[(size_t)bl * HH + tid + 128];
  __syncthreads();
  const float4* a4 = reinterpret_cast<const float4*>(A + ((size_t)b * LL + tid) * HH);
  const float4* q4 = reinterpret_cast<const float4*>(qs);
  float acc = 0.f;
#pragma unroll 8
  for (int h = 0; h < HH / 4; ++h) {
    float4 av = a4[h], qv = q4[h];
    acc += av.x * qv.x + av.y * qv.y + av.z * qv.z + av.w * qv.w;
  }
  float mx = acc;
#pragma unroll
  for (int off = 32; off; off >>= 1) mx = fmaxf(mx, __shfl_xor(mx, off));
  if (lane == 0) red[wv] = mx;
  __syncthreads();
  mx = fmaxf(red[0], red[1]);
  float e = expf(acc - mx);
  float sm = e;
#pragma unroll
  for (int off = 32; off; off >>= 1) sm += __shfl_xor(sm, off);
  if (lane == 0) red[2 + wv] = sm;
  __syncthreads();
  sm = red[2] + red[3];
  score[(size_t)bl * LL + tid] = acc;
  wq[(size_t)bl * LL + tid] = e / sm;
}

// ---------------------------------------------------------------- softmax over l (cols) -> waT[b][m][l]
__global__ __launch_bounds__(64) void softmax_col(const float* __restrict__ score,
                                                  float* __restrict__ waT) {
  const int bm = blockIdx.x;
  const int b = bm >> 7, m = bm & 127;
  const int lane = threadIdx.x;
  const float* s = score + (size_t)b * LL * LL + m;
  float x0 = s[(size_t)lane * LL], x1 = s[(size_t)(lane + 64) * LL];
  float mx = fmaxf(x0, x1);
#pragma unroll
  for (int off = 32; off; off >>= 1) mx = fmaxf(mx, __shfl_xor(mx, off));
  float e0 = expf(x0 - mx), e1 = expf(x1 - mx);
  float sum = e0 + e1;
#pragma unroll
  for (int off = 32; off; off >>= 1) sum += __shfl_xor(sum, off);
  float inv = 1.f / sum;
  waT[(size_t)bm * LL + lane] = e0 * inv;
  waT[(size_t)bm * LL + lane + 64] = e1 * inv;
}

// ---------------------------------------------------------------- align+encode: EQ/EA + match features -> Tbf
__global__ __launch_bounds__(1024) void align_encode(const float* __restrict__ wq,
                                                     const float* __restrict__ waT,
                                                     const float* __restrict__ Q,
                                                     const float* __restrict__ A,
                                                     u16* __restrict__ Tbf) {
  __shared__ float wl[128 * 128];
  __shared__ float sl[128 * 64];
  const int bid = blockIdx.x;
  const int side = bid >> 7;
  const int b = (bid >> 2) & 31;
  const int h0 = (bid & 3) * 64;
  const int tid = threadIdx.x;
  const int lt = tid >> 6, hx = tid & 63;

  const float* wsrc = (side ? waT : wq) + (size_t)b * (LL * LL);
  const float* ssrc = (side ? Q : A) + (size_t)b * (LL * HH) + h0;
  const float* msrc = (side ? A : Q) + (size_t)b * (LL * HH) + h0;

#pragma unroll
  for (int i = 0; i < 16; ++i) {
    int idx = i * 1024 + tid;
    wl[idx] = wsrc[idx];
  }
#pragma unroll
  for (int i = 0; i < 8; ++i) {
    int idx = i * 1024 + tid;
    int r = idx >> 6, c = idx & 63;
    sl[idx] = ssrc[(size_t)r * HH + c];
  }
  __syncthreads();

  float accv[8];
#pragma unroll
  for (int ii = 0; ii < 8; ++ii) accv[ii] = 0.f;

  for (int j4 = 0; j4 < 128; j4 += 4) {
    float s0 = sl[(j4 + 0) * 64 + hx];
    float s1 = sl[(j4 + 1) * 64 + hx];
    float s2 = sl[(j4 + 2) * 64 + hx];
    float s3 = sl[(j4 + 3) * 64 + hx];
#pragma unroll
    for (int ii = 0; ii < 8; ++ii) {
      float4 wv = *reinterpret_cast<const float4*>(&wl[(lt + 16 * ii) * 128 + j4]);
      accv[ii] += wv.x * s0 + wv.y * s1 + wv.z * s2 + wv.w * s3;
    }
  }

  u16* outp = Tbf + (size_t)(side * 4096 + b * 128) * 512 + h0;
#pragma unroll
  for (int ii = 0; ii < 8; ++ii) {
    int i = lt + 16 * ii;
    float mv = msrc[(size_t)i * HH + hx];
    float e = accv[ii];
    float d = mv - e;
    outp[(size_t)i * 512 + hx] = f2bf_rne(d * d);
    outp[(size_t)i * 512 + 256 + hx] = f2bf_rne(mv * e);
  }
}

// ---------------------------------------------------------------- Wcat bf16 [1024][512]
__global__ __launch_bounds__(256) void prep_wcat(const float* __restrict__ w0,
                                                 const float* __restrict__ w1,
                                                 const float* __restrict__ w2,
                                                 const float* __restrict__ w3,
                                                 u16* __restrict__ Wcat) {
  const int kr = blockIdx.x;
  const int tid = threadIdx.x;
  u16* out = Wcat + (size_t)kr * 512;
  if (kr >= KK * 10) {
    out[tid] = 0;
    out[tid + 256] = 0;
    return;
  }
  const int k = kr / 10, s = kr % 10;
  const float* w;
  int r, fs;
  if (s < 1)      { w = w0; r = s;     fs = 1; }
  else if (s < 3) { w = w1; r = s - 1; fs = 2; }
  else if (s < 6) { w = w2; r = s - 3; fs = 3; }
  else            { w = w3; r = s - 6; fs = 4; }
  const float* src = w + ((size_t)k * fs + r) * 522 + 5;
  out[tid] = f2bf_rne(src[tid]);
  out[tid + 256] = f2bf_rne(src[tid + 256]);
}

// ---------------------------------------------------------------- conv GEMM: D[8192][1024] = Tbf @ Wcat^T
// Same m97 skeleton, A bf16. grid (64,4). LDS 48 KB.
__global__ __launch_bounds__(512, 4) void gemm_conv(const u16* __restrict__ Tbf,
                                                    const u16* __restrict__ Wcat,
                                                    float* __restrict__ D) {
  __shared__ __align__(16) u16 As[128 * 64];   // 16 KB
  __shared__ __align__(16) u16 Bs[256 * 64];   // 32 KB
  const int tid = threadIdx.x;
  const int lane = tid & 63, wid = tid >> 6;
  const int wm = wid >> 2, wn = wid & 3;
  const int m0 = blockIdx.x * 128;
  const int n0 = blockIdx.y * 256;

  f32x4 acc[4][4];
  const f32x4 zf = {0.f, 0.f, 0.f, 0.f};
#pragma unroll
  for (int i = 0; i < 4; ++i)
#pragma unroll
    for (int j = 0; j < 4; ++j) acc[i][j] = zf;

  const int browL = (lane >> 3);
  const int bkL = (lane & 7) << 3;

  for (int s = 0; s < STEPS2; ++s) {
    const int ks = s * 64;
#pragma unroll
    for (int j = 0; j < 2; ++j) {
      int rowA = (wid << 4) + (j << 3) + browL;
      int kA = bkL ^ ((rowA & 7) << 3);
      gld16(Tbf + (size_t)(m0 + rowA) * 512 + ks + kA, (void*)&As[(wid * 2 + j) * 512]);
    }
#pragma unroll
    for (int j = 0; j < 4; ++j) {
      int rowB = (wid << 5) + (j << 3) + browL;
      int kB = bkL ^ ((rowB & 7) << 3);
      gld16(Wcat + (size_t)(n0 + rowB) * 512 + ks + kB, (void*)&Bs[(wid * 4 + j) * 512]);
    }
    __syncthreads();
#pragma unroll
    for (int kk = 0; kk < 64; kk += 32) {
      const int krow = kk + ((lane >> 4) << 3);
      bf16x8 af[4], bfr[4];
#pragma unroll
      for (int mi = 0; mi < 4; ++mi) {
        int row = wm * 64 + mi * 16 + (lane & 15);
        af[mi] = *reinterpret_cast<const bf16x8*>(&As[row * 64 + (krow ^ ((row & 7) << 3))]);
      }
#pragma unroll
      for (int ni = 0; ni < 4; ++ni) {
        int row = wn * 64 + ni * 16 + (lane & 15);
        bfr[ni] = *reinterpret_cast<const bf16x8*>(&Bs[row * 64 + (krow ^ ((row & 7) << 3))]);
      }
#pragma unroll
      for (int mi = 0; mi < 4; ++mi)
#pragma unroll
        for (int ni = 0; ni < 4; ++ni)
          acc[mi][ni] = __builtin_amdgcn_mfma_f32_16x16x32_bf16(af[mi], bfr[ni], acc[mi][ni], 0, 0, 0);
    }
    __syncthreads();
  }

  const int r0 = (lane >> 4) << 2;
  const int coln = n0 + wn * 64 + (lane & 15);
#pragma unroll
  for (int mi = 0; mi < 4; ++mi)
#pragma unroll
    for (int ni = 0; ni < 4; ++ni)
#pragma unroll
      for (int r = 0; r < 4; ++r)
        D[(size_t)(m0 + wm * 64 + mi * 16 + r0 + r) * NPAD + coln + ni * 16] = acc[mi][ni][r];
}

// ---------------------------------------------------------------- shift-sum + bias + relu + maxpool -> re[32][800]
__global__ __launch_bounds__(256) void reduce_conv(const float* __restrict__ D,
                                                   const float* __restrict__ b0,
                                                   const float* __restrict__ b1,
                                                   const float* __restrict__ b2,
                                                   const float* __restrict__ b3,
                                                   float* __restrict__ re) {
  __shared__ float tile[128][101];
  const int pair = blockIdx.y;
  const int sel = pair >> 5, b = pair & 31;
  const int kc = blockIdx.x;
  const int tid = threadIdx.x;
  const int rowbase = sel * (BB * LL) + b * LL;
  const int c0 = kc * 100;
  for (int idx = tid; idx < 12800; idx += 256) {
    int r = idx / 100, c = idx - r * 100;
    tile[r][c] = D[(size_t)(rowbase + r) * NPAD + c0 + c];
  }
  __syncthreads();
  const int wid = tid >> 6, lane = tid & 63;
  const int offt[4] = {0, 1, 3, 6};
  const int fst[4] = {1, 2, 3, 4};
  for (int o = wid; o < 40; o += 4) {
    const int kk = o >> 2, f = o & 3;
    const int fs = fst[f], off = offt[f];
    const int kg = kc * 10 + kk;
    const float bias = (f == 0 ? b0 : f == 1 ? b1 : f == 2 ? b2 : b3)[kg];
    const int col = kk * 10 + off;
    const int outh = 139 - fs;
    float best = 0.f;
    for (int i = lane; i < outh; i += 64) {
      float s = bias;
#pragma unroll 4
      for (int r = 0; r < 4; ++r) {
        if (r < fs) {
          int j = i + r - 5;
          if (j >= 0 && j < LL) s += tile[j][col + r];
        }
      }
      best = fmaxf(best, s);
    }
    best = fmaxf(best, 0.f);
#pragma unroll
    for (int d = 32; d; d >>= 1) best = fmaxf(best, __shfl_xor(best, d));
    if (lane == 0) re[(size_t)b * 800 + sel * 400 + f * 100 + kg] = best;
  }
}

// ---------------------------------------------------------------- dense + log_softmax -> out[32][2]
__global__ __launch_bounds__(64) void dense_logsm(const float* __restrict__ re,
                                                  const float* __restrict__ dw,
                                                  const float* __restrict__ db,
                                                  float* __restrict__ out) {
  const int b = blockIdx.x;
  const int lane = threadIdx.x;
  const float* r = re + (size_t)b * 800;
  float a0 = 0.f, a1 = 0.f;
  for (int j = lane; j < 800; j += 64) {
    float rv = r[j];
    a0 += rv * dw[j * 2];
    a1 += rv * dw[j * 2 + 1];
  }
#pragma unroll
  for (int d = 32; d; d >>= 1) {
    a0 += __shfl_xor(a0, d);
    a1 += __shfl_xor(a1, d);
  }
  if (lane == 0) {
    a0 += db[0];
    a1 += db[1];
    float mx = fmaxf(a0, a1);
    float lse = mx + logf(expf(a0 - mx) + expf(a1 - mx));
    out[b * 2] = a0 - lse;
    out[b * 2 + 1] = a1 - lse;
  }
}

// ---------------------------------------------------------------- workspace layout (bytes)
static const size_t OFF_PARTS = 0;                         // 8 * 8192*256 f32 = 67,108,864
static const size_t OFF_D     = 0;                         // alias (parts dead by conv time)
static const size_t OFF_Q     = 67108864;
static const size_t OFF_A     = OFF_Q + 4194304;
static const size_t OFF_SCORE = OFF_A + 4194304;
static const size_t OFF_WQ    = OFF_SCORE + 2097152;
static const size_t OFF_WAT   = OFF_WQ + 2097152;
static const size_t OFF_RE    = OFF_WAT + 2097152;
static const size_t OFF_TBF   = OFF_RE + 102400;
static const size_t OFF_WCAT  = OFF_TBF + 8388608;
static const size_t OFF_EMBT  = OFF_WCAT + 1048576;

extern "C" void kernel_launch(void* const* d_in, const int* in_sizes, int n_in,
                              void* d_out, int out_size, void* d_ws, size_t ws_size,
                              hipStream_t stream) {
  (void)in_sizes; (void)n_in; (void)out_size; (void)ws_size;
  const float* adj  = (const float*)d_in[0];
  const float* emb  = (const float*)d_in[1];
  const int* q_idx  = (const int*)d_in[2];
  const int* a_idx  = (const int*)d_in[3];
  const float* cw0 = (const float*)d_in[4];
  const float* cb0 = (const float*)d_in[5];
  const float* cw1 = (const float*)d_in[6];
  const float* cb1 = (const float*)d_in[7];
  const float* cw2 = (const float*)d_in[8];
  const float* cb2 = (const float*)d_in[9];
  const float* cw3 = (const float*)d_in[10];
  const float* cb3 = (const float*)d_in[11];
  const float* dw = (const float*)d_in[12];
  const float* db = (const float*)d_in[13];
  float* out = (float*)d_out;

  char* ws = (char*)d_ws;
  float* parts = (float*)(ws + OFF_PARTS);
  float* Dbuf  = (float*)(ws + OFF_D);
  float* Q     = (float*)(ws + OFF_Q);
  float* Abuf  = (float*)(ws + OFF_A);
  float* score = (float*)(ws + OFF_SCORE);
  float* wq    = (float*)(ws + OFF_WQ);
  float* waT   = (float*)(ws + OFF_WAT);
  float* re    = (float*)(ws + OFF_RE);
  u16* Tbf     = (u16*)(ws + OFF_TBF);
  u16* Wcat    = (u16*)(ws + OFF_WCAT);
  u16* embT    = (u16*)(ws + OFF_EMBT);

  convert_embT<<<dim3(128, 4), 256, 0, stream>>>(emb, embT);
  prep_wcat<<<1024, 256, 0, stream>>>(cw0, cw1, cw2, cw3, Wcat);
  gemm_layer1<<<64 * SPLITK, 512, 0, stream>>>(adj, embT, parts);
  gather_qa<<<2 * BB * LL, 256, 0, stream>>>(parts, q_idx, a_idx, Q, Abuf);
  score_row<<<BB * LL, 128, 0, stream>>>(Q, Abuf, score, wq);
  softmax_col<<<BB * LL, 64, 0, stream>>>(score, waT);
  align_encode<<<256, 1024, 0, stream>>>(wq, waT, Q, Abuf, Tbf);
  gemm_conv<<<dim3(64, 4), 512, 0, stream>>>(Tbf, Wcat, Dbuf);
  reduce_conv<<<dim3(10, 64), 256, 0, stream>>>(Dbuf, cb0, cb1, cb2, cb3, re);
  dense_logsm<<<BB, 64, 0, stream>>>(re, dw, db, out);
}